// Round 2
// baseline (253012.354 us; speedup 1.0000x reference)
//
#include <hip/hip_runtime.h>
#include <hip/hip_bf16.h>
#include <hip/hip_fp16.h>

// Problem constants
#define T_STEPS 8192
#define O_DIM   1024
#define H_DIM   2048
#define G3      6144      // 3*H
#define A_DIM   512
#define NWG     256       // workgroups in scan (1 per CU)
#define SLICE   8         // H_DIM / NWG hidden indices per WG
#define NROWS   24        // 3 * SLICE rows of W_hh per WG
#define RPW     6         // rows per wave (24 rows / 4 waves)
#define KPL     32        // 2048 / 64 k-elements per lane

// Workspace row stride for the X buffer (one row per timestep + 1):
// each row is 12288 B = 6144 fp16 (xi) and doubles, one step later, as
// 3072 fp32 of which the first 2048 hold hs[t].
#define XROW_BYTES 12288
#define XROW_F32   3072

// ---------------------------------------------------------------------------
// fp32 GEMM:  C[M,N] = A[M,K] @ B[N,K]^T + bias[N]
// 128x128 tile, BK=16, 256 threads, 8x8 per thread.
// OUT_HALF=1 stores C as fp16 (packed 8-wide), else fp32.
// A has row stride lda; C has row stride ldc; B is dense [N,K].
// ---------------------------------------------------------------------------
template <int OUT_HALF>
__global__ __launch_bounds__(256) void gemm_bt_bias(
    const float* __restrict__ A, int lda,
    const float* __restrict__ B,
    const float* __restrict__ bias,
    void* __restrict__ Cv, int ldc,
    int M, int N, int K)
{
    __shared__ float As[16][128];   // As[k][m]
    __shared__ float Bs[16][128];   // Bs[k][n]

    const int bm = blockIdx.y * 128;
    const int bn = blockIdx.x * 128;
    const int tid = threadIdx.x;
    const int tm = (tid >> 4) * 8;
    const int tn = (tid & 15) * 8;

    float acc[8][8] = {};

    for (int k0 = 0; k0 < K; k0 += 16) {
        #pragma unroll
        for (int u = 0; u < 2; ++u) {
            const int id = u * 256 + tid;
            const int r = id >> 2;
            const int c = (id & 3) << 2;
            float4 v = *(const float4*)(A + (size_t)(bm + r) * lda + k0 + c);
            As[c + 0][r] = v.x; As[c + 1][r] = v.y;
            As[c + 2][r] = v.z; As[c + 3][r] = v.w;
        }
        #pragma unroll
        for (int u = 0; u < 2; ++u) {
            const int id = u * 256 + tid;
            const int r = id >> 2;
            const int c = (id & 3) << 2;
            float4 v = *(const float4*)(B + (size_t)(bn + r) * K + k0 + c);
            Bs[c + 0][r] = v.x; Bs[c + 1][r] = v.y;
            Bs[c + 2][r] = v.z; Bs[c + 3][r] = v.w;
        }
        __syncthreads();

        #pragma unroll
        for (int kk = 0; kk < 16; ++kk) {
            float a[8], b[8];
            #pragma unroll
            for (int i = 0; i < 8; ++i) a[i] = As[kk][tm + i];
            #pragma unroll
            for (int j = 0; j < 8; ++j) b[j] = Bs[kk][tn + j];
            #pragma unroll
            for (int i = 0; i < 8; ++i)
                #pragma unroll
                for (int j = 0; j < 8; ++j)
                    acc[i][j] = fmaf(a[i], b[j], acc[i][j]);
        }
        __syncthreads();
    }

    if (OUT_HALF) {
        __half* C = (__half*)Cv;
        #pragma unroll
        for (int i = 0; i < 8; ++i) {
            const size_t row = (size_t)(bm + tm + i) * ldc;
            __half tmp[8];
            #pragma unroll
            for (int j = 0; j < 8; ++j)
                tmp[j] = __float2half(acc[i][j] + bias[bn + tn + j]);
            *(uint4*)(C + row + bn + tn) = *(const uint4*)tmp;
        }
    } else {
        float* C = (float*)Cv;
        #pragma unroll
        for (int i = 0; i < 8; ++i) {
            const size_t row = (size_t)(bm + tm + i) * ldc;
            #pragma unroll
            for (int j0 = 0; j0 < 8; j0 += 4) {
                const int n = bn + tn + j0;
                float4 v;
                v.x = acc[i][j0 + 0] + bias[n + 0];
                v.y = acc[i][j0 + 1] + bias[n + 1];
                v.z = acc[i][j0 + 2] + bias[n + 2];
                v.w = acc[i][j0 + 3] + bias[n + 3];
                *(float4*)(C + row + n) = v;
            }
        }
    }
}

// ---------------------------------------------------------------------------
// Persistent cooperative GRU scan.
// 256 WGs x 256 threads. WG g owns hidden indices [8g, 8g+8) -> 24 rows of
// W_hh held in registers (fp32, 192 VGPR/lane). One device-wide barrier per
// step; h ping-pong double-buffered in global memory.
// X buffer: row t+1 holds xi[t] (fp16[6144]); hs[t] (fp32[2048]) is written
// into row t (whose xi was consumed at step t-1 -> race-free).
// ---------------------------------------------------------------------------
__global__ __launch_bounds__(256, 1) void gru_scan(
    const __half* __restrict__ xiX,   // X as fp16 rows (stride 6144)
    float*        __restrict__ hsX,   // X as fp32 rows (stride 3072)
    const float*  __restrict__ W_hh,  // [6144, 2048]
    const float*  __restrict__ b_hh,  // [6144]
    float* __restrict__ h_pp,         // [2, 2048], buf 0 pre-zeroed
    unsigned* __restrict__ bar)       // [0]=count, [1]=generation, pre-zeroed
{
    const int g    = blockIdx.x;
    const int tid  = threadIdx.x;
    const int wave = tid >> 6;
    const int lane = tid & 63;

    // ---- load W_hh slice into registers -----------------------------------
    float w[RPW][KPL];
    #pragma unroll
    for (int r = 0; r < RPW; ++r) {
        const int l = wave * RPW + r;                          // 0..23
        const int grow = (l >> 3) * H_DIM + g * SLICE + (l & 7);
        const float* wp = W_hh + (size_t)grow * H_DIM + lane;
        #pragma unroll
        for (int m = 0; m < KPL; ++m) w[r][m] = wp[m * 64];
    }

    __shared__ float gh_lds[NROWS];
    __shared__ float bh_lds[NROWS];
    __shared__ float xi_lds[NROWS];
    if (tid < NROWS)
        bh_lds[tid] = b_hh[(tid >> 3) * H_DIM + g * SLICE + (tid & 7)];
    __syncthreads();

    unsigned gen = 0;
    for (int t = 0; t < T_STEPS; ++t) {
        const float* hin  = h_pp + (t & 1) * H_DIM;
        float*       hout = h_pp + ((t + 1) & 1) * H_DIM;

        // prefetch this step's xi entries (row t+1 of X)
        float xpre = 0.f;
        if (tid < NROWS)
            xpre = __half2float(
                xiX[(size_t)(t + 1) * G3 + (tid >> 3) * H_DIM + g * SLICE + (tid & 7)]);

        // load h (coalesced: lane l reads h[l + 64m])
        float hreg[KPL];
        #pragma unroll
        for (int m = 0; m < KPL; ++m) hreg[m] = hin[lane + m * 64];

        // matvec partials: 6 rows x 32 k per lane
        float acc[RPW] = {0.f, 0.f, 0.f, 0.f, 0.f, 0.f};
        #pragma unroll
        for (int m = 0; m < KPL; ++m)
            #pragma unroll
            for (int r = 0; r < RPW; ++r)
                acc[r] = fmaf(w[r][m], hreg[m], acc[r]);

        // reduce each row across the 64 lanes
        #pragma unroll
        for (int r = 0; r < RPW; ++r) {
            float a = acc[r];
            #pragma unroll
            for (int off = 32; off >= 1; off >>= 1)
                a += __shfl_xor(a, off, 64);
            if (lane == 0) gh_lds[wave * RPW + r] = a;
        }
        if (tid < NROWS) xi_lds[tid] = xpre;
        __syncthreads();

        // gate math for this WG's 8 hidden indices
        if (tid < SLICE) {
            const int i = g * SLICE + tid;
            const float ghr = gh_lds[tid]      + bh_lds[tid];
            const float ghz = gh_lds[8 + tid]  + bh_lds[8 + tid];
            const float ghn = gh_lds[16 + tid] + bh_lds[16 + tid];
            const float xr = xi_lds[tid];
            const float xz = xi_lds[8 + tid];
            const float xn = xi_lds[16 + tid];
            const float rg = 1.f / (1.f + expf(-(xr + ghr)));
            const float zg = 1.f / (1.f + expf(-(xz + ghz)));
            const float ng = tanhf(xn + rg * ghn);
            const float hnew = (1.f - zg) * ng + zg * hin[i];
            hout[i] = hnew;
            hsX[(size_t)t * XROW_F32 + i] = hnew;   // row t of X (consumed)
        }
        __syncthreads();

        // device-wide barrier (monotone generation, no sense reversal)
        if (tid == 0) {
            __threadfence();   // release this WG's hout/hs writes (agent scope)
            unsigned arrived = __hip_atomic_fetch_add(
                &bar[0], 1u, __ATOMIC_ACQ_REL, __HIP_MEMORY_SCOPE_AGENT);
            if (arrived == NWG - 1) {
                __hip_atomic_store(&bar[0], 0u, __ATOMIC_RELAXED,
                                   __HIP_MEMORY_SCOPE_AGENT);
                __hip_atomic_store(&bar[1], gen + 1u, __ATOMIC_RELEASE,
                                   __HIP_MEMORY_SCOPE_AGENT);
            } else {
                while (__hip_atomic_load(&bar[1], __ATOMIC_ACQUIRE,
                                         __HIP_MEMORY_SCOPE_AGENT) == gen) {
                    __builtin_amdgcn_s_sleep(1);
                }
            }
            __threadfence();   // acquire remote writes before next step
        }
        ++gen;
        __syncthreads();
    }
}

// ---------------------------------------------------------------------------
extern "C" void kernel_launch(void* const* d_in, const int* in_sizes, int n_in,
                              void* d_out, int out_size, void* d_ws, size_t ws_size,
                              hipStream_t stream) {
    const float* obs  = (const float*)d_in[0];
    const float* W_ih = (const float*)d_in[1];
    const float* W_hh = (const float*)d_in[2];
    const float* b_ih = (const float*)d_in[3];
    const float* b_hh = (const float*)d_in[4];
    const float* W_o  = (const float*)d_in[5];
    const float* b_o  = (const float*)d_in[6];
    const float* W_d  = (const float*)d_in[7];
    const float* b_d  = (const float*)d_in[8];
    float* out = (float*)d_out;

    // Workspace layout (total ~96.1 MiB):
    //   [0, 8)        barrier (2 x u32)
    //   [4096, 20480) h ping-pong (2 x 2048 fp32)
    //   [32768, ...)  X buffer: (T+1) rows x 12288 B
    char* ws = (char*)d_ws;
    unsigned* bar  = (unsigned*)ws;
    float*    h_pp = (float*)(ws + 4096);
    char*     X    = ws + 32768;
    __half*   xiX  = (__half*)X;   // fp16 rows, stride 6144
    float*    hsX  = (float*)X;    // fp32 rows, stride 3072

    hipMemsetAsync(d_ws, 0, 32768, stream);

    // Phase 1: xi[t] = obs @ W_ih.T + b_ih  -> fp16 into X row t+1
    gemm_bt_bias<1><<<dim3(G3 / 128, T_STEPS / 128), 256, 0, stream>>>(
        obs, O_DIM, W_ih, b_ih, (void*)(xiX + G3), G3, T_STEPS, G3, O_DIM);

    // Phase 2: sequential GRU scan (cooperative, all 256 CUs)
    {
        void* args[] = { (void*)&xiX, (void*)&hsX, (void*)&W_hh, (void*)&b_hh,
                         (void*)&h_pp, (void*)&bar };
        hipLaunchCooperativeKernel((const void*)gru_scan,
                                   dim3(NWG), dim3(256), args, 0, stream);
    }

    // Phase 3: output projections (A = hs rows inside X, lda = 3072)
    gemm_bt_bias<0><<<dim3(A_DIM / 128, T_STEPS / 128), 256, 0, stream>>>(
        (const float*)hsX, XROW_F32, W_o, b_o, (void*)out, A_DIM,
        T_STEPS, A_DIM, H_DIM);
    gemm_bt_bias<0><<<dim3(A_DIM / 128, T_STEPS / 128), 256, 0, stream>>>(
        (const float*)hsX, XROW_F32, W_d, b_d,
        (void*)(out + (size_t)T_STEPS * A_DIM), A_DIM,
        T_STEPS, A_DIM, H_DIM);
}

// Round 3
// 100507.086 us; speedup vs baseline: 2.5174x; 2.5174x over previous
//
#include <hip/hip_runtime.h>
#include <hip/hip_bf16.h>
#include <hip/hip_fp16.h>

// Problem constants
#define T_STEPS 8192
#define O_DIM   1024
#define H_DIM   2048
#define G3      6144      // 3*H
#define A_DIM   512
#define NWG     256       // workgroups in scan (1 per CU)
#define SLICE   8         // hidden indices per WG
#define NROWS   24        // 3 * SLICE rows of W_hh per WG
#define NWAVES  8         // 512 threads
#define RPW     3         // rows per wave (24 / 8)
#define NJ      8         // float4 k-groups per lane (8 * 256 = 2048)

// X buffer rows: row t+1 holds xi[t] as fp16[6144]; hs[t] (fp32[2048]) is
// written into row t after its xi was consumed.
#define XROW_F32   3072

// ---------------------------------------------------------------------------
// fp32 GEMM:  C[M,N] = A[M,K] @ B[N,K]^T + bias[N]
// 128x128 tile, BK=16, 256 threads, 8x8 per thread.
// OUT_HALF=1 stores C as fp16, else fp32. A row stride lda, C row stride ldc.
// ---------------------------------------------------------------------------
template <int OUT_HALF>
__global__ __launch_bounds__(256) void gemm_bt_bias(
    const float* __restrict__ A, int lda,
    const float* __restrict__ B,
    const float* __restrict__ bias,
    void* __restrict__ Cv, int ldc,
    int M, int N, int K)
{
    __shared__ float As[16][128];
    __shared__ float Bs[16][128];

    const int bm = blockIdx.y * 128;
    const int bn = blockIdx.x * 128;
    const int tid = threadIdx.x;
    const int tm = (tid >> 4) * 8;
    const int tn = (tid & 15) * 8;

    float acc[8][8] = {};

    for (int k0 = 0; k0 < K; k0 += 16) {
        #pragma unroll
        for (int u = 0; u < 2; ++u) {
            const int id = u * 256 + tid;
            const int r = id >> 2;
            const int c = (id & 3) << 2;
            float4 v = *(const float4*)(A + (size_t)(bm + r) * lda + k0 + c);
            As[c + 0][r] = v.x; As[c + 1][r] = v.y;
            As[c + 2][r] = v.z; As[c + 3][r] = v.w;
        }
        #pragma unroll
        for (int u = 0; u < 2; ++u) {
            const int id = u * 256 + tid;
            const int r = id >> 2;
            const int c = (id & 3) << 2;
            float4 v = *(const float4*)(B + (size_t)(bn + r) * K + k0 + c);
            Bs[c + 0][r] = v.x; Bs[c + 1][r] = v.y;
            Bs[c + 2][r] = v.z; Bs[c + 3][r] = v.w;
        }
        __syncthreads();

        #pragma unroll
        for (int kk = 0; kk < 16; ++kk) {
            float a[8], b[8];
            #pragma unroll
            for (int i = 0; i < 8; ++i) a[i] = As[kk][tm + i];
            #pragma unroll
            for (int j = 0; j < 8; ++j) b[j] = Bs[kk][tn + j];
            #pragma unroll
            for (int i = 0; i < 8; ++i)
                #pragma unroll
                for (int j = 0; j < 8; ++j)
                    acc[i][j] = fmaf(a[i], b[j], acc[i][j]);
        }
        __syncthreads();
    }

    if (OUT_HALF) {
        __half* C = (__half*)Cv;
        #pragma unroll
        for (int i = 0; i < 8; ++i) {
            const size_t row = (size_t)(bm + tm + i) * ldc;
            __half tmp[8];
            #pragma unroll
            for (int j = 0; j < 8; ++j)
                tmp[j] = __float2half(acc[i][j] + bias[bn + tn + j]);
            *(uint4*)(C + row + bn + tn) = *(const uint4*)tmp;
        }
    } else {
        float* C = (float*)Cv;
        #pragma unroll
        for (int i = 0; i < 8; ++i) {
            const size_t row = (size_t)(bm + tm + i) * ldc;
            #pragma unroll
            for (int j0 = 0; j0 < 8; j0 += 4) {
                const int n = bn + tn + j0;
                float4 v;
                v.x = acc[i][j0 + 0] + bias[n + 0];
                v.y = acc[i][j0 + 1] + bias[n + 1];
                v.z = acc[i][j0 + 2] + bias[n + 2];
                v.w = acc[i][j0 + 3] + bias[n + 3];
                *(float4*)(C + row + n) = v;
            }
        }
    }
}

// ---------------------------------------------------------------------------
// Persistent cooperative GRU scan, v2.
// 256 WGs x 512 threads (8 waves). WG g owns hidden idx [8g, 8g+8):
// 24 rows of W_hh, 3 rows/wave, float4 w4[3][8] = 96 VGPR/lane.
// Cross-WG sync: per-WG progress flags + agent-scope cache-bypassing
// atomics for h exchange. NO fences, NO central barrier -> caches with
// W_hh/xi are never invalidated.
// Per step:
//   wave1: prefetch xi (plain cached load)
//   wave0: poll 256 flags >= t; load h (agent atomics) -> LDS
//   sync A; all waves: ds_read h, 3-row matvec, shuffle-reduce -> gh_lds
//   wave1: xi -> LDS; sync B
//   wave0 lanes<8: gates; h_out agent store; hs plain store;
//          s_waitcnt vmcnt(0); lane0: flags[g] = t+1
// ---------------------------------------------------------------------------
__global__ __launch_bounds__(512, 2) void gru_scan(
    const __half* __restrict__ xiX,   // X as fp16 rows (stride 6144)
    float*        __restrict__ hsX,   // X as fp32 rows (stride 3072)
    const float*  __restrict__ W_hh,  // [6144, 2048]
    const float*  __restrict__ b_hh,  // [6144]
    float* __restrict__ h_pp,         // [2, 2048], buf 0 pre-zeroed
    unsigned* __restrict__ flags)     // [256], pre-zeroed
{
    const int g    = blockIdx.x;
    const int tid  = threadIdx.x;
    const int wave = tid >> 6;
    const int lane = tid & 63;

    // ---- load W_hh slice into registers (float4, coalesced) ---------------
    float4 w4[RPW][NJ];
    #pragma unroll
    for (int r = 0; r < RPW; ++r) {
        const int l = wave * RPW + r;                          // 0..23
        const int grow = (l >> 3) * H_DIM + g * SLICE + (l & 7);
        const float* wp = W_hh + (size_t)grow * H_DIM + lane * 4;
        #pragma unroll
        for (int j = 0; j < NJ; ++j)
            w4[r][j] = *(const float4*)(wp + j * 256);
    }

    __shared__ float h_lds[H_DIM];
    __shared__ float gh_lds[NROWS];
    __shared__ float bh_lds[NROWS];
    __shared__ float xi_lds[NROWS];
    if (tid < NROWS)
        bh_lds[tid] = b_hh[(tid >> 3) * H_DIM + g * SLICE + (tid & 7)];
    __syncthreads();

    for (int t = 0; t < T_STEPS; ++t) {
        const float* hin  = h_pp + (t & 1) * H_DIM;
        float*       hout = h_pp + ((t + 1) & 1) * H_DIM;

        // wave1: prefetch xi for this step (row t+1 of X), plain cached load
        float xpre = 0.f;
        if (wave == 1 && lane < NROWS)
            xpre = __half2float(
                xiX[(size_t)(t + 1) * G3 + (lane >> 3) * H_DIM + g * SLICE + (lane & 7)]);

        // wave0: wait for all producers of step t, then stage h into LDS
        if (wave == 0) {
            const unsigned tgt = (unsigned)t;
            const unsigned* f4 = flags + lane * 4;
            for (;;) {
                unsigned m0 = __hip_atomic_load(f4 + 0, __ATOMIC_RELAXED, __HIP_MEMORY_SCOPE_AGENT);
                unsigned m1 = __hip_atomic_load(f4 + 1, __ATOMIC_RELAXED, __HIP_MEMORY_SCOPE_AGENT);
                unsigned m2 = __hip_atomic_load(f4 + 2, __ATOMIC_RELAXED, __HIP_MEMORY_SCOPE_AGENT);
                unsigned m3 = __hip_atomic_load(f4 + 3, __ATOMIC_RELAXED, __HIP_MEMORY_SCOPE_AGENT);
                unsigned mn = min(min(m0, m1), min(m2, m3));
                if (__all(mn >= tgt)) break;
                __builtin_amdgcn_s_sleep(1);
            }
            __asm__ __volatile__("" ::: "memory");   // pin compiler ordering
            #pragma unroll
            for (int m = 0; m < 32; ++m) {
                float hv = __hip_atomic_load(hin + lane + m * 64,
                                             __ATOMIC_RELAXED, __HIP_MEMORY_SCOPE_AGENT);
                h_lds[lane + m * 64] = hv;
            }
        }
        __syncthreads();   // A: h_lds ready

        // all waves: 3-row matvec from LDS
        float4 h4[NJ];
        #pragma unroll
        for (int j = 0; j < NJ; ++j)
            h4[j] = *(const float4*)(h_lds + j * 256 + lane * 4);

        float acc[RPW] = {0.f, 0.f, 0.f};
        #pragma unroll
        for (int j = 0; j < NJ; ++j) {
            #pragma unroll
            for (int r = 0; r < RPW; ++r) {
                acc[r] = fmaf(w4[r][j].x, h4[j].x, acc[r]);
                acc[r] = fmaf(w4[r][j].y, h4[j].y, acc[r]);
                acc[r] = fmaf(w4[r][j].z, h4[j].z, acc[r]);
                acc[r] = fmaf(w4[r][j].w, h4[j].w, acc[r]);
            }
        }

        #pragma unroll
        for (int r = 0; r < RPW; ++r) {
            float a = acc[r];
            #pragma unroll
            for (int off = 32; off >= 1; off >>= 1)
                a += __shfl_xor(a, off, 64);
            if (lane == 0) gh_lds[wave * RPW + r] = a;
        }
        if (wave == 1 && lane < NROWS) xi_lds[lane] = xpre;
        __syncthreads();   // B: gh_lds + xi_lds ready

        if (wave == 0) {
            if (lane < SLICE) {
                const int i = g * SLICE + lane;
                const float ghr = gh_lds[lane]      + bh_lds[lane];
                const float ghz = gh_lds[8 + lane]  + bh_lds[8 + lane];
                const float ghn = gh_lds[16 + lane] + bh_lds[16 + lane];
                const float xr = xi_lds[lane];
                const float xz = xi_lds[8 + lane];
                const float xn = xi_lds[16 + lane];
                const float rg = 1.f / (1.f + __expf(-(xr + ghr)));
                const float zg = 1.f / (1.f + __expf(-(xz + ghz)));
                const float ng = tanhf(xn + rg * ghn);
                const float hprev = h_lds[i];
                const float hnew = (1.f - zg) * ng + zg * hprev;
                __hip_atomic_store(hout + i, hnew,
                                   __ATOMIC_RELAXED, __HIP_MEMORY_SCOPE_AGENT);
                hsX[(size_t)t * XROW_F32 + i] = hnew;   // plain (read post-kernel)
            }
            __asm__ __volatile__("s_waitcnt vmcnt(0)" ::: "memory");
            if (lane == 0)
                __hip_atomic_store(flags + g, (unsigned)(t + 1),
                                   __ATOMIC_RELAXED, __HIP_MEMORY_SCOPE_AGENT);
        }
        // no third sync: waves 1..7 stall at next step's sync A until wave0
        // arrives (after its flag store), protecting gh_lds/xi_lds/h_lds.
    }
}

// ---------------------------------------------------------------------------
extern "C" void kernel_launch(void* const* d_in, const int* in_sizes, int n_in,
                              void* d_out, int out_size, void* d_ws, size_t ws_size,
                              hipStream_t stream) {
    const float* obs  = (const float*)d_in[0];
    const float* W_ih = (const float*)d_in[1];
    const float* W_hh = (const float*)d_in[2];
    const float* b_ih = (const float*)d_in[3];
    const float* b_hh = (const float*)d_in[4];
    const float* W_o  = (const float*)d_in[5];
    const float* b_o  = (const float*)d_in[6];
    const float* W_d  = (const float*)d_in[7];
    const float* b_d  = (const float*)d_in[8];
    float* out = (float*)d_out;

    // Workspace layout (~100.8 MiB total):
    //   [0, 1024)       flags (256 x u32)
    //   [4096, 20480)   h ping-pong (2 x 2048 fp32)
    //   [32768, ...)    X buffer: (T+1) rows x 12288 B
    char*     ws    = (char*)d_ws;
    unsigned* flags = (unsigned*)ws;
    float*    h_pp  = (float*)(ws + 4096);
    char*     X     = ws + 32768;
    __half*   xiX   = (__half*)X;   // fp16 rows, stride 6144
    float*    hsX   = (float*)X;    // fp32 rows, stride 3072

    hipMemsetAsync(d_ws, 0, 32768, stream);

    // Phase 1: xi[t] = obs @ W_ih.T + b_ih  -> fp16 into X row t+1
    gemm_bt_bias<1><<<dim3(G3 / 128, T_STEPS / 128), 256, 0, stream>>>(
        obs, O_DIM, W_ih, b_ih, (void*)(xiX + G3), G3, T_STEPS, G3, O_DIM);

    // Phase 2: sequential GRU scan (cooperative, 256 WGs x 512 threads)
    {
        void* args[] = { (void*)&xiX, (void*)&hsX, (void*)&W_hh, (void*)&b_hh,
                         (void*)&h_pp, (void*)&flags };
        hipLaunchCooperativeKernel((const void*)gru_scan,
                                   dim3(NWG), dim3(512), args, 0, stream);
    }

    // Phase 3: output projections (A = hs rows inside X, lda = 3072)
    gemm_bt_bias<0><<<dim3(A_DIM / 128, T_STEPS / 128), 256, 0, stream>>>(
        (const float*)hsX, XROW_F32, W_o, b_o, (void*)out, A_DIM,
        T_STEPS, A_DIM, H_DIM);
    gemm_bt_bias<0><<<dim3(A_DIM / 128, T_STEPS / 128), 256, 0, stream>>>(
        (const float*)hsX, XROW_F32, W_d, b_d,
        (void*)(out + (size_t)T_STEPS * A_DIM), A_DIM,
        T_STEPS, A_DIM, H_DIM);
}

// Round 4
// 26120.944 us; speedup vs baseline: 9.6862x; 3.8478x over previous
//
#include <hip/hip_runtime.h>
#include <hip/hip_bf16.h>
#include <hip/hip_fp16.h>

// Problem constants
#define T_STEPS 8192
#define O_DIM   1024
#define H_DIM   2048
#define G3      6144      // 3*H
#define A_DIM   512
#define NWG     256       // workgroups in scan (1 per CU)
#define SLICE   8         // hidden indices per WG
#define NROWS   24        // 3 * SLICE rows of W_hh per WG
#define RPW     3         // rows per wave (24 / 8 waves)
#define NJ      8         // float4 k-groups per lane (8 * 256 = 2048)

// X buffer rows: row t+1 holds xi[t] as fp16[6144]; hs[t] (fp32[2048]) is
// written into row t after its xi was consumed.
#define XROW_F32   3072

// ---------------------------------------------------------------------------
// fp32 GEMM:  C[M,N] = A[M,K] @ B[N,K]^T + bias[N]
// 128x128 tile, BK=16, 256 threads, 8x8 per thread.
// OUT_HALF=1 stores C as fp16, else fp32. A row stride lda, C row stride ldc.
// ---------------------------------------------------------------------------
template <int OUT_HALF>
__global__ __launch_bounds__(256) void gemm_bt_bias(
    const float* __restrict__ A, int lda,
    const float* __restrict__ B,
    const float* __restrict__ bias,
    void* __restrict__ Cv, int ldc,
    int M, int N, int K)
{
    __shared__ float As[16][128];
    __shared__ float Bs[16][128];

    const int bm = blockIdx.y * 128;
    const int bn = blockIdx.x * 128;
    const int tid = threadIdx.x;
    const int tm = (tid >> 4) * 8;
    const int tn = (tid & 15) * 8;

    float acc[8][8] = {};

    for (int k0 = 0; k0 < K; k0 += 16) {
        #pragma unroll
        for (int u = 0; u < 2; ++u) {
            const int id = u * 256 + tid;
            const int r = id >> 2;
            const int c = (id & 3) << 2;
            float4 v = *(const float4*)(A + (size_t)(bm + r) * lda + k0 + c);
            As[c + 0][r] = v.x; As[c + 1][r] = v.y;
            As[c + 2][r] = v.z; As[c + 3][r] = v.w;
        }
        #pragma unroll
        for (int u = 0; u < 2; ++u) {
            const int id = u * 256 + tid;
            const int r = id >> 2;
            const int c = (id & 3) << 2;
            float4 v = *(const float4*)(B + (size_t)(bn + r) * K + k0 + c);
            Bs[c + 0][r] = v.x; Bs[c + 1][r] = v.y;
            Bs[c + 2][r] = v.z; Bs[c + 3][r] = v.w;
        }
        __syncthreads();

        #pragma unroll
        for (int kk = 0; kk < 16; ++kk) {
            float a[8], b[8];
            #pragma unroll
            for (int i = 0; i < 8; ++i) a[i] = As[kk][tm + i];
            #pragma unroll
            for (int j = 0; j < 8; ++j) b[j] = Bs[kk][tn + j];
            #pragma unroll
            for (int i = 0; i < 8; ++i)
                #pragma unroll
                for (int j = 0; j < 8; ++j)
                    acc[i][j] = fmaf(a[i], b[j], acc[i][j]);
        }
        __syncthreads();
    }

    if (OUT_HALF) {
        __half* C = (__half*)Cv;
        #pragma unroll
        for (int i = 0; i < 8; ++i) {
            const size_t row = (size_t)(bm + tm + i) * ldc;
            __half tmp[8];
            #pragma unroll
            for (int j = 0; j < 8; ++j)
                tmp[j] = __float2half(acc[i][j] + bias[bn + tn + j]);
            *(uint4*)(C + row + bn + tn) = *(const uint4*)tmp;
        }
    } else {
        float* C = (float*)Cv;
        #pragma unroll
        for (int i = 0; i < 8; ++i) {
            const size_t row = (size_t)(bm + tm + i) * ldc;
            #pragma unroll
            for (int j0 = 0; j0 < 8; j0 += 4) {
                const int n = bn + tn + j0;
                float4 v;
                v.x = acc[i][j0 + 0] + bias[n + 0];
                v.y = acc[i][j0 + 1] + bias[n + 1];
                v.z = acc[i][j0 + 2] + bias[n + 2];
                v.w = acc[i][j0 + 3] + bias[n + 3];
                *(float4*)(C + row + n) = v;
            }
        }
    }
}

// ---------------------------------------------------------------------------
// Persistent cooperative GRU scan, v3.
// 256 WGs x 512 threads (8 waves), 1 WG/CU. WG g owns hidden idx [8g,8g+8):
// 24 rows of W_hh, 3 rows/wave, float4 w4[3][8] = 96 VGPR/lane, PINNED in
// registers (waves_per_eu(2,2) -> 256-VGPR budget + asm pin).
// Cross-WG h exchange: tagged 8-byte pairs (fp32 value | u32 step tag),
// relaxed agent-scope 64-bit atomics -> single coherence round trip, no
// fences, no cache invalidates.
// Per step:
//   waves 0/2/4/6: poll own 512-pair chunk (tag==t), stage h -> LDS
//   wave1: prefetch xi (plain cached load)
//   sync A; all waves: 3-row matvec from LDS, shuffle-reduce -> gh_lds
//   wave1: xi -> LDS; sync B
//   wave0 lanes<8: gates; store (hnew | t+1) pair; store hs row
// ---------------------------------------------------------------------------
__global__ __launch_bounds__(512) __attribute__((amdgpu_waves_per_eu(2, 2)))
void gru_scan(
    const __half*  __restrict__ xiX,     // X as fp16 rows (stride 6144)
    float*         __restrict__ hsX,     // X as fp32 rows (stride 3072)
    const float*   __restrict__ W_hh,    // [6144, 2048]
    const float*   __restrict__ b_hh,    // [6144]
    unsigned long long* __restrict__ h_pairs)  // [2, 2048] pairs, pre-zeroed
{
    const int g    = blockIdx.x;
    const int tid  = threadIdx.x;
    const int wave = tid >> 6;
    const int lane = tid & 63;

    // ---- load W_hh slice into registers (float4, coalesced) ---------------
    float4 w4[RPW][NJ];
    #pragma unroll
    for (int r = 0; r < RPW; ++r) {
        const int l = wave * RPW + r;                          // 0..23
        const int grow = (l >> 3) * H_DIM + g * SLICE + (l & 7);
        const float* wp = W_hh + (size_t)grow * H_DIM + lane * 4;
        #pragma unroll
        for (int j = 0; j < NJ; ++j)
            w4[r][j] = *(const float4*)(wp + j * 256);
    }
    // Pin weights into VGPRs: opaque to the optimizer -> cannot be sunk
    // back into the loop as re-loads.
    #pragma unroll
    for (int r = 0; r < RPW; ++r)
        #pragma unroll
        for (int j = 0; j < NJ; ++j)
            asm volatile("" : "+v"(w4[r][j].x), "+v"(w4[r][j].y),
                              "+v"(w4[r][j].z), "+v"(w4[r][j].w));

    __shared__ float h_lds[H_DIM];
    __shared__ float gh_lds[NROWS];
    __shared__ float bh_lds[NROWS];
    __shared__ float xi_lds[NROWS];
    if (tid < NROWS)
        bh_lds[tid] = b_hh[(tid >> 3) * H_DIM + g * SLICE + (tid & 7)];
    __syncthreads();

    for (int t = 0; t < T_STEPS; ++t) {
        // wave1: prefetch xi for this step (row t+1 of X), plain cached load
        float xpre = 0.f;
        if (wave == 1 && lane < NROWS)
            xpre = __half2float(
                xiX[(size_t)(t + 1) * G3 + (lane >> 3) * H_DIM + g * SLICE + (lane & 7)]);

        // waves 0/2/4/6: poll own chunk of tagged pairs, stage h into LDS
        if ((wave & 1) == 0) {
            const int chunk = wave >> 1;                       // 0..3
            const unsigned long long* pp =
                h_pairs + (size_t)(t & 1) * H_DIM + chunk * 512 + lane;
            unsigned long long p[8];
            for (;;) {
                #pragma unroll
                for (int m = 0; m < 8; ++m)
                    p[m] = __hip_atomic_load(pp + m * 64, __ATOMIC_RELAXED,
                                             __HIP_MEMORY_SCOPE_AGENT);
                bool ok = true;
                #pragma unroll
                for (int m = 0; m < 8; ++m)
                    ok &= ((unsigned)(p[m] >> 32) == (unsigned)t);
                if (__all(ok)) break;
                __builtin_amdgcn_s_sleep(2);
            }
            #pragma unroll
            for (int m = 0; m < 8; ++m)
                h_lds[chunk * 512 + lane + m * 64] =
                    __uint_as_float((unsigned)p[m]);
        }
        __syncthreads();   // A: h_lds ready

        // all waves: 3-row matvec from LDS
        float4 h4[NJ];
        #pragma unroll
        for (int j = 0; j < NJ; ++j)
            h4[j] = *(const float4*)(h_lds + j * 256 + lane * 4);

        float acc[RPW] = {0.f, 0.f, 0.f};
        #pragma unroll
        for (int j = 0; j < NJ; ++j) {
            #pragma unroll
            for (int r = 0; r < RPW; ++r) {
                acc[r] = fmaf(w4[r][j].x, h4[j].x, acc[r]);
                acc[r] = fmaf(w4[r][j].y, h4[j].y, acc[r]);
                acc[r] = fmaf(w4[r][j].z, h4[j].z, acc[r]);
                acc[r] = fmaf(w4[r][j].w, h4[j].w, acc[r]);
            }
        }

        #pragma unroll
        for (int r = 0; r < RPW; ++r) {
            float a = acc[r];
            #pragma unroll
            for (int off = 32; off >= 1; off >>= 1)
                a += __shfl_xor(a, off, 64);
            if (lane == 0) gh_lds[wave * RPW + r] = a;
        }
        if (wave == 1 && lane < NROWS) xi_lds[lane] = xpre;
        __syncthreads();   // B: gh_lds + xi_lds ready

        if (wave == 0 && lane < SLICE) {
            const int i = g * SLICE + lane;
            const float ghr = gh_lds[lane]      + bh_lds[lane];
            const float ghz = gh_lds[8 + lane]  + bh_lds[8 + lane];
            const float ghn = gh_lds[16 + lane] + bh_lds[16 + lane];
            const float xr = xi_lds[lane];
            const float xz = xi_lds[8 + lane];
            const float xn = xi_lds[16 + lane];
            const float rg = 1.f / (1.f + __expf(-(xr + ghr)));
            const float zg = 1.f / (1.f + __expf(-(xz + ghz)));
            const float ng = tanhf(xn + rg * ghn);
            const float hprev = h_lds[i];     // own chunk: safe post-sync-B
            const float hnew = (1.f - zg) * ng + zg * hprev;
            const unsigned long long pr =
                ((unsigned long long)(unsigned)(t + 1) << 32) |
                (unsigned long long)__float_as_uint(hnew);
            __hip_atomic_store(h_pairs + (size_t)((t + 1) & 1) * H_DIM + i, pr,
                               __ATOMIC_RELAXED, __HIP_MEMORY_SCOPE_AGENT);
            hsX[(size_t)t * XROW_F32 + i] = hnew;   // read after kernel end
        }
        // no third sync: next step's sync A protects the LDS buffers; the
        // chunk containing this WG's own pairs cannot pass its poll until
        // the stores above are visible.
    }
}

// ---------------------------------------------------------------------------
extern "C" void kernel_launch(void* const* d_in, const int* in_sizes, int n_in,
                              void* d_out, int out_size, void* d_ws, size_t ws_size,
                              hipStream_t stream) {
    const float* obs  = (const float*)d_in[0];
    const float* W_ih = (const float*)d_in[1];
    const float* W_hh = (const float*)d_in[2];
    const float* b_ih = (const float*)d_in[3];
    const float* b_hh = (const float*)d_in[4];
    const float* W_o  = (const float*)d_in[5];
    const float* b_o  = (const float*)d_in[6];
    const float* W_d  = (const float*)d_in[7];
    const float* b_d  = (const float*)d_in[8];
    float* out = (float*)d_out;

    // Workspace layout (~100.8 MiB total):
    //   [4096, 36864)   h tagged pairs (2 x 2048 x 8 B), pre-zeroed
    //   [65536, ...)    X buffer: (T+1) rows x 12288 B
    char*  ws = (char*)d_ws;
    unsigned long long* h_pairs = (unsigned long long*)(ws + 4096);
    char*   X   = ws + 65536;
    __half* xiX = (__half*)X;   // fp16 rows, stride 6144
    float*  hsX = (float*)X;    // fp32 rows, stride 3072

    hipMemsetAsync(d_ws, 0, 65536, stream);

    // Phase 1: xi[t] = obs @ W_ih.T + b_ih  -> fp16 into X row t+1
    gemm_bt_bias<1><<<dim3(G3 / 128, T_STEPS / 128), 256, 0, stream>>>(
        obs, O_DIM, W_ih, b_ih, (void*)(xiX + G3), G3, T_STEPS, G3, O_DIM);

    // Phase 2: sequential GRU scan (cooperative, 256 WGs x 512 threads)
    {
        void* args[] = { (void*)&xiX, (void*)&hsX, (void*)&W_hh, (void*)&b_hh,
                         (void*)&h_pairs };
        hipLaunchCooperativeKernel((const void*)gru_scan,
                                   dim3(NWG), dim3(512), args, 0, stream);
    }

    // Phase 3: output projections (A = hs rows inside X, lda = 3072)
    gemm_bt_bias<0><<<dim3(A_DIM / 128, T_STEPS / 128), 256, 0, stream>>>(
        (const float*)hsX, XROW_F32, W_o, b_o, (void*)out, A_DIM,
        T_STEPS, A_DIM, H_DIM);
    gemm_bt_bias<0><<<dim3(A_DIM / 128, T_STEPS / 128), 256, 0, stream>>>(
        (const float*)hsX, XROW_F32, W_d, b_d,
        (void*)(out + (size_t)T_STEPS * A_DIM), A_DIM,
        T_STEPS, A_DIM, H_DIM);
}